// Round 1
// 242.429 us; speedup vs baseline: 1.0602x; 1.0602x over previous
//
#include <hip/hip_runtime.h>
#include <hip/hip_bf16.h>
#include <stdint.h>

typedef __bf16 bf16;
typedef __bf16 bf16x8 __attribute__((ext_vector_type(8)));
typedef float  f32x4  __attribute__((ext_vector_type(4)));

#define BM 128
#define BN 128
#define BK 64
#define E  512
#define SB 4112            // per-batch extended row stride (4098 valid + 14 pad)
#define M1 (8 * SB)        // 32896 = 128 * 257 extended rows
#define M2 32768           // output rows

__device__ __forceinline__ void gl_lds_16(const bf16* g, bf16* l) {
    __builtin_amdgcn_global_load_lds(
        (__attribute__((address_space(1))) void*)g,
        (__attribute__((address_space(3))) void*)l,
        16, 0, 0);
}

// ---------------- GEMM1: C[m,n] = sum_k A[m,k]*B[n,k], bf16 out ----------------
// BK=64 (half the barrier drains vs BK=32).  LDS tiles are [128][64] bf16 with a
// 128B row stride -> would be a 16-way bank conflict on ds_read_b128, so the
// 16B chunks within each row are XOR-swizzled by (row&7).  global_load_lds
// writes linearly (dest = base + lane*16B), so the swizzle is applied to the
// per-lane GLOBAL source address (rule: linear dest + inv-swz source + swz read).
__global__ __launch_bounds__(256)
void gemm_bt_bf16(const bf16* __restrict__ A, const bf16* __restrict__ Bm,
                  bf16* __restrict__ C, int M, int N, int K)
{
    __shared__ bf16 As[BM * BK];
    __shared__ bf16 Bs[BN * BK];

    const int tid  = threadIdx.x;
    const int id   = blockIdx.x;          // 1D grid: 4 bn-blocks of a bm adjacent
    const int bm   = id >> 2;
    const int bn   = id & 3;
    const int wave = tid >> 6;
    const int lane = tid & 63;
    const int wm   = wave >> 1;
    const int wn   = wave & 1;

    // staging: thread tid stages LDS row (call*32 + tid>>3), chunk (tid&7).
    // That LDS chunk c' must hold logical k-chunk (c' ^ (row&7)).
    const int srow = tid >> 3;                       // 0..31
    const int scol = (((tid & 7) ^ (srow & 7)) << 3); // swizzled source col (elems)
    const size_t a_off = (size_t)(bm * BM + srow) * K + scol;
    const size_t b_off = (size_t)(bn * BN + srow) * K + scol;
    const int    l_off = tid * 8;                    // linear: lane*16B per call

    f32x4 acc[4][4] = {};
    const int fr = lane & 15;
    const int q  = lane >> 4;                        // k-chunk within 32-col half

    for (int k0 = 0; k0 < K; k0 += BK) {
#pragma unroll
        for (int c = 0; c < 4; ++c) {                // 4 calls x 32 rows each
            gl_lds_16(A  + a_off + (size_t)(c * 32) * K + k0, As + c * 2048 + l_off);
            gl_lds_16(Bm + b_off + (size_t)(c * 32) * K + k0, Bs + c * 2048 + l_off);
        }
        __syncthreads();

#pragma unroll
        for (int t = 0; t < 2; ++t) {                // two 32-wide k sub-steps
            bf16x8 af[4], bfr[4];
#pragma unroll
            for (int i = 0; i < 4; ++i) {
                const int Ra = wm * 64 + i * 16 + fr;
                const int Rb = wn * 64 + i * 16 + fr;
                const int c  = t * 4 + q;            // logical 16B chunk 0..7
                af[i]  = *(const bf16x8*)(As + Ra * BK + ((c ^ (Ra & 7)) << 3));
                bfr[i] = *(const bf16x8*)(Bs + Rb * BK + ((c ^ (Rb & 7)) << 3));
            }
#pragma unroll
            for (int i = 0; i < 4; ++i)
#pragma unroll
                for (int j = 0; j < 4; ++j)
                    acc[i][j] = __builtin_amdgcn_mfma_f32_16x16x32_bf16(af[i], bfr[j], acc[i][j], 0, 0, 0);
        }
        __syncthreads();
    }

    const int crow = (lane >> 4) << 2;
    const int ccol = lane & 15;
    const int row0 = bm * BM + wm * 64 + crow;
    const int col0 = bn * BN + wn * 64 + ccol;
#pragma unroll
    for (int i = 0; i < 4; ++i)
#pragma unroll
        for (int j = 0; j < 4; ++j)
#pragma unroll
            for (int r = 0; r < 4; ++r)
                C[(size_t)(row0 + i * 16 + r) * N + (col0 + j * 16)] = (bf16)acc[i][j][r];
}

// ------- GEMM2: A gathered with per-head row shift; fp32 out ------------------
// A2[m=(b,s), k] = P[b*SB + s + 1 + sh(k>>6), k]; sh uniform per K-iter (BK=64
// == one head).  Same BK=64 + swizzle + 1D-grid treatment as GEMM1.
__global__ __launch_bounds__(256)
void gemm2_gather(const bf16* __restrict__ P, const bf16* __restrict__ Bm,
                  float* __restrict__ C)
{
    __shared__ bf16 As[BM * BK];
    __shared__ bf16 Bs[BN * BK];

    const int tid  = threadIdx.x;
    const int id   = blockIdx.x;
    const int bm   = id >> 2;
    const int bn   = id & 3;
    const int wave = tid >> 6;
    const int lane = tid & 63;
    const int wm   = wave >> 1;
    const int wn   = wave & 1;

    const int srow = tid >> 3;                        // 0..31
    const int scol = (((tid & 7) ^ (srow & 7)) << 3);
    const size_t b_off = (size_t)(bn * BN + srow) * E + scol;
    const int    l_off = tid * 8;

    f32x4 acc[4][4] = {};
    const int fr = lane & 15;
    const int q  = lane >> 4;

    for (int k0 = 0; k0 < E; k0 += BK) {
        const int h3 = (k0 >> 6) & 3;                       // head pattern %4
        const int sh = (h3 == 1) ? -1 : (h3 == 2) ? 1 : 0;  // wave-uniform
#pragma unroll
        for (int c = 0; c < 4; ++c) {
            const int m = bm * BM + c * 32 + srow;          // output row staged
            const int prow = (m >> 12) * SB + (m & 4095) + 1 + sh;
            gl_lds_16(P  + (size_t)prow * E + k0 + scol,          As + c * 2048 + l_off);
            gl_lds_16(Bm + b_off + (size_t)(c * 32) * E + k0,     Bs + c * 2048 + l_off);
        }
        __syncthreads();

#pragma unroll
        for (int t = 0; t < 2; ++t) {
            bf16x8 af[4], bfr[4];
#pragma unroll
            for (int i = 0; i < 4; ++i) {
                const int Ra = wm * 64 + i * 16 + fr;
                const int Rb = wn * 64 + i * 16 + fr;
                const int c  = t * 4 + q;
                af[i]  = *(const bf16x8*)(As + Ra * BK + ((c ^ (Ra & 7)) << 3));
                bfr[i] = *(const bf16x8*)(Bs + Rb * BK + ((c ^ (Rb & 7)) << 3));
            }
#pragma unroll
            for (int i = 0; i < 4; ++i)
#pragma unroll
                for (int j = 0; j < 4; ++j)
                    acc[i][j] = __builtin_amdgcn_mfma_f32_16x16x32_bf16(af[i], bfr[j], acc[i][j], 0, 0, 0);
        }
        __syncthreads();
    }

    const int crow = (lane >> 4) << 2;
    const int ccol = lane & 15;
    const int row0 = bm * BM + wm * 64 + crow;
    const int col0 = bn * BN + wn * 64 + ccol;
#pragma unroll
    for (int i = 0; i < 4; ++i)
#pragma unroll
        for (int j = 0; j < 4; ++j)
#pragma unroll
            for (int r = 0; r < 4; ++r)
                C[(size_t)(row0 + i * 16 + r) * E + (col0 + j * 16)] = acc[i][j][r];
}

// ------- prefilter: VG[b, r, e] = sum_j filt[j] * values[b, r-1+j-2, e] -------
// v2: one thread produces 8 consecutive extended rows x 8 channels via a
// register sliding window: 12 input-row loads per 8 rows written (1.5x re-read
// instead of 5x).  All bounds branches are wave-uniform (whole wave shares the
// row group; lane = channel chunk).  Rows >= 4098 may hold small garbage; they
// are never read downstream (gemm2 reads extended rows [0,4098) only).
__global__ __launch_bounds__(256)
void prefilter(const float* __restrict__ vals, bf16* __restrict__ vg)
{
    const int tid  = threadIdx.x;
    const int e8   = tid & 63;                       // channel chunk (8 floats)
    const int gidx = blockIdx.x * 4 + (tid >> 6);    // row group [0, M1/8)
    const int m0   = gidx << 3;                      // first extended row
    const int b    = m0 / SB;                        // group never straddles batch (SB%8==0)
    const int r0   = m0 - b * SB;                    // [0, 4112)

    const float filt[5] = {0.05399096651318806f, 0.24197072451914337f,
                           0.3989422804014327f,
                           0.24197072451914337f, 0.05399096651318806f};

    float acc[8][8];
#pragma unroll
    for (int t = 0; t < 8; ++t)
#pragma unroll
        for (int d = 0; d < 8; ++d) acc[t][d] = 0.f;

    const float* bbase = vals + (size_t)b * 4096 * E + e8 * 8;
#pragma unroll
    for (int u = 0; u < 12; ++u) {                   // inputs sp = r0-3 .. r0+8
        const int sp = r0 - 3 + u;
        if (sp >= 0 && sp < 4096) {
            const f32x4* p = (const f32x4*)(bbase + (size_t)sp * E);
            const f32x4 x0 = p[0], x1 = p[1];
            const float x[8] = {x0[0], x0[1], x0[2], x0[3],
                                x1[0], x1[1], x1[2], x1[3]};
#pragma unroll
            for (int t = 0; t < 8; ++t) {            // out row r0+t needs j = u-t
                const int j = u - t;
                if (j >= 0 && j < 5) {
                    const float w = filt[j];
#pragma unroll
                    for (int d = 0; d < 8; ++d) acc[t][d] += w * x[d];
                }
            }
        }
    }
#pragma unroll
    for (int t = 0; t < 8; ++t) {
        bf16x8 o;
#pragma unroll
        for (int d = 0; d < 8; ++d) o[d] = (bf16)acc[t][d];
        *((bf16x8*)vg + (size_t)(m0 + t) * 64 + e8) = o;
    }
}

// ------- weight convert: both 512x512 fp32 matrices -> bf16 in one launch -----
__global__ __launch_bounds__(256)
void cvt_weights(const float* __restrict__ w_in, const float* __restrict__ w_out,
                 bf16* __restrict__ win_b, bf16* __restrict__ wout_b)
{
    const int i = blockIdx.x * 256 + threadIdx.x;      // [0, 2*512*512/8)
    const int half = (E * E) / 8;                      // 32768
    const float* src = (i < half) ? w_in : w_out;
    bf16* dst        = (i < half) ? win_b : wout_b;
    const int k = (i < half) ? i : i - half;
    const f32x4* p = (const f32x4*)src + 2 * (size_t)k;
    f32x4 a = p[0], bq = p[1];
    bf16x8 o;
    o[0] = (bf16)a[0]; o[1] = (bf16)a[1]; o[2] = (bf16)a[2]; o[3] = (bf16)a[3];
    o[4] = (bf16)bq[0]; o[5] = (bf16)bq[1]; o[6] = (bf16)bq[2]; o[7] = (bf16)bq[3];
    *((bf16x8*)dst + k) = o;
}

extern "C" void kernel_launch(void* const* d_in, const int* in_sizes, int n_in,
                              void* d_out, int out_size, void* d_ws, size_t ws_size,
                              hipStream_t stream)
{
    const float* values = (const float*)d_in[0];
    // d_in[1]=keys, d_in[2]=queries: unused by the reference path (no QK^T)
    const float* w_in   = (const float*)d_in[3];
    const float* w_out  = (const float*)d_in[4];
    float* out = (float*)d_out;

    // workspace: weights 1 MB + VG 33.7 MB + P 33.7 MB ~= 68.4 MB
    bf16* win_b  = (bf16*)d_ws;                 // 512*512
    bf16* wout_b = win_b + E * E;               // 512*512
    bf16* vg     = wout_b + E * E;              // M1*E
    bf16* Pbuf   = vg + (size_t)M1 * E;         // M1*E

    cvt_weights<<<(2 * E * E / 8) / 256, 256, 0, stream>>>(w_in, w_out, win_b, wout_b);
    prefilter<<<M1 / 8 / 4, 256, 0, stream>>>(values, vg);

    // 1D grids, bn fastest: the 4 column-blocks sharing an A-panel run adjacently
    gemm_bt_bf16<<<(M1 / BM) * 4, 256, 0, stream>>>(vg, win_b, Pbuf, M1, E, E);
    gemm2_gather<<<(M2 / BM) * 4, 256, 0, stream>>>(Pbuf, wout_b, out);
}

// Round 2
// 241.934 us; speedup vs baseline: 1.0623x; 1.0020x over previous
//
#include <hip/hip_runtime.h>
#include <hip/hip_bf16.h>
#include <stdint.h>

typedef __bf16 bf16;
typedef __bf16 bf16x8 __attribute__((ext_vector_type(8)));
typedef float  f32x4  __attribute__((ext_vector_type(4)));

#define BM 128
#define BN 128
#define BK 64
#define E  512
#define SB 4112            // per-batch extended row stride (4098 valid + 14 pad)
#define M1 (8 * SB)        // 32896 = 128 * 257 extended rows
#define M2 32768           // output rows

__device__ __forceinline__ void gl_lds_16(const bf16* g, bf16* l) {
    __builtin_amdgcn_global_load_lds(
        (__attribute__((address_space(1))) void*)g,
        (__attribute__((address_space(3))) void*)l,
        16, 0, 0);
}

// ---------------- GEMM1: C[m,n] = sum_k A[m,k]*B[n,k], bf16 out ----------------
// Unchanged from round 1 (multi-resident 128x128, BK=64, XOR swizzle, 1D grid).
// 129 M-tiles at 256^2 would quantize to 2 block-rounds at 1 blk/CU, so the
// big-tile prefetch structure is reserved for gemm2 whose grid fits exactly.
__global__ __launch_bounds__(256)
void gemm_bt_bf16(const bf16* __restrict__ A, const bf16* __restrict__ Bm,
                  bf16* __restrict__ C, int M, int N, int K)
{
    __shared__ bf16 As[BM * BK];
    __shared__ bf16 Bs[BN * BK];

    const int tid  = threadIdx.x;
    const int id   = blockIdx.x;          // 1D grid: 4 bn-blocks of a bm adjacent
    const int bm   = id >> 2;
    const int bn   = id & 3;
    const int wave = tid >> 6;
    const int lane = tid & 63;
    const int wm   = wave >> 1;
    const int wn   = wave & 1;

    const int srow = tid >> 3;                       // 0..31
    const int scol = (((tid & 7) ^ (srow & 7)) << 3); // swizzled source col (elems)
    const size_t a_off = (size_t)(bm * BM + srow) * K + scol;
    const size_t b_off = (size_t)(bn * BN + srow) * K + scol;
    const int    l_off = tid * 8;                    // linear: lane*16B per call

    f32x4 acc[4][4] = {};
    const int fr = lane & 15;
    const int q  = lane >> 4;                        // k-chunk within 32-col half

    for (int k0 = 0; k0 < K; k0 += BK) {
#pragma unroll
        for (int c = 0; c < 4; ++c) {                // 4 calls x 32 rows each
            gl_lds_16(A  + a_off + (size_t)(c * 32) * K + k0, As + c * 2048 + l_off);
            gl_lds_16(Bm + b_off + (size_t)(c * 32) * K + k0, Bs + c * 2048 + l_off);
        }
        __syncthreads();

#pragma unroll
        for (int t = 0; t < 2; ++t) {                // two 32-wide k sub-steps
            bf16x8 af[4], bfr[4];
#pragma unroll
            for (int i = 0; i < 4; ++i) {
                const int Ra = wm * 64 + i * 16 + fr;
                const int Rb = wn * 64 + i * 16 + fr;
                const int c  = t * 4 + q;            // logical 16B chunk 0..7
                af[i]  = *(const bf16x8*)(As + Ra * BK + ((c ^ (Ra & 7)) << 3));
                bfr[i] = *(const bf16x8*)(Bs + Rb * BK + ((c ^ (Rb & 7)) << 3));
            }
#pragma unroll
            for (int i = 0; i < 4; ++i)
#pragma unroll
                for (int j = 0; j < 4; ++j)
                    acc[i][j] = __builtin_amdgcn_mfma_f32_16x16x32_bf16(af[i], bfr[j], acc[i][j], 0, 0, 0);
        }
        __syncthreads();
    }

    const int crow = (lane >> 4) << 2;
    const int ccol = lane & 15;
    const int row0 = bm * BM + wm * 64 + crow;
    const int col0 = bn * BN + wn * 64 + ccol;
#pragma unroll
    for (int i = 0; i < 4; ++i)
#pragma unroll
        for (int j = 0; j < 4; ++j)
#pragma unroll
            for (int r = 0; r < 4; ++r)
                C[(size_t)(row0 + i * 16 + r) * N + (col0 + j * 16)] = (bf16)acc[i][j][r];
}

// ------- GEMM2 v2: 256x256 tile, 8 waves, double-buffered full-tile prefetch --
// Grid = 128 x 2 = exactly 256 blocks = 1 block/CU.  Per K-tile: issue ALL 8
// global_load_lds of tile t+1 into buf p^1 at tile start, then 4 compute
// sub-phases read buf p (ds_read + MFMA only), then ONE __syncthreads (compiler
// emits vmcnt(0) lgkmcnt(0) there) -- the 8 loads get ~4 phases of MFMA to
// land, so the drain is nearly free.  A-rows gathered with per-head shift
// (BK=64 == one head, wave-uniform per tile).  XOR chunk swizzle as gemm1.
__global__ __launch_bounds__(512, 2)
void gemm2_gather(const bf16* __restrict__ P, const bf16* __restrict__ Bm,
                  float* __restrict__ C)
{
    __shared__ bf16 As[2][256 * 64];
    __shared__ bf16 Bs[2][256 * 64];

    const int tid  = threadIdx.x;
    const int id   = blockIdx.x;
    const int bm   = id >> 1;             // 0..127
    const int bn   = id & 1;              // 0..1
    const int wave = tid >> 6;            // 0..7
    const int lane = tid & 63;
    const int wm   = wave >> 2;           // 0..1  (128 rows each)
    const int wn   = wave & 3;            // 0..3  (64 cols each)

    const int srow = tid >> 3;                         // 0..63
    const int scol = (((tid & 7) ^ (srow & 7)) << 3);  // pre-swizzled source col
    const int ldst = tid * 8;                          // elems into a 4096-slab

    f32x4 acc[8][4] = {};
    const int fr = lane & 15;
    const int q  = lane >> 4;

    // ---- stage tile t into buffer p (8 x 16B/thread = 64 KB total) ----
    auto stage = [&](int t, int p) {
        const int k0 = t << 6;
        const int h3 = t & 3;
        const int sh = (h3 == 1) ? -1 : (h3 == 2) ? 1 : 0;   // wave-uniform
#pragma unroll
        for (int c = 0; c < 4; ++c) {
            const int m    = bm * 256 + c * 64 + srow;
            const int prow = (m >> 12) * SB + (m & 4095) + 1 + sh;
            gl_lds_16(P + (size_t)prow * E + k0 + scol, &As[p][c * 4096 + ldst]);
        }
#pragma unroll
        for (int c = 0; c < 4; ++c) {
            const int n = bn * 256 + c * 64 + srow;
            gl_lds_16(Bm + (size_t)n * E + k0 + scol, &Bs[p][c * 4096 + ldst]);
        }
    };

    stage(0, 0);
    __syncthreads();                       // drain prologue loads

    for (int t = 0; t < 8; ++t) {
        const int p = t & 1;
        if (t < 7) stage(t + 1, p ^ 1);    // 8 loads in flight across the tile
        __builtin_amdgcn_s_setprio(1);
#pragma unroll
        for (int ih = 0; ih < 2; ++ih) {
            bf16x8 af[4][2];
#pragma unroll
            for (int ii = 0; ii < 4; ++ii)
#pragma unroll
                for (int ks = 0; ks < 2; ++ks) {
                    const int Ra = wm * 128 + (ih * 4 + ii) * 16 + fr;
                    const int ch = ks * 4 + q;
                    af[ii][ks] = *(const bf16x8*)(&As[p][Ra * 64 + ((ch ^ (Ra & 7)) << 3)]);
                }
#pragma unroll
            for (int jh = 0; jh < 2; ++jh) {
                bf16x8 bfv[2][2];
#pragma unroll
                for (int jj = 0; jj < 2; ++jj)
#pragma unroll
                    for (int ks = 0; ks < 2; ++ks) {
                        const int Rb = wn * 64 + (jh * 2 + jj) * 16 + fr;
                        const int ch = ks * 4 + q;
                        bfv[jj][ks] = *(const bf16x8*)(&Bs[p][Rb * 64 + ((ch ^ (Rb & 7)) << 3)]);
                    }
#pragma unroll
                for (int ii = 0; ii < 4; ++ii)
#pragma unroll
                    for (int jj = 0; jj < 2; ++jj)
#pragma unroll
                        for (int ks = 0; ks < 2; ++ks)
                            acc[ih * 4 + ii][jh * 2 + jj] =
                                __builtin_amdgcn_mfma_f32_16x16x32_bf16(
                                    af[ii][ks], bfv[jj][ks],
                                    acc[ih * 4 + ii][jh * 2 + jj], 0, 0, 0);
            }
        }
        __builtin_amdgcn_s_setprio(0);
        __syncthreads();                   // vmcnt(0)+lgkmcnt(0): tile t+1 ready,
    }                                      // all waves done reading buf p

    const int crow = (lane >> 4) << 2;
    const int ccol = lane & 15;
    const int row0 = bm * 256 + wm * 128 + crow;
    const int col0 = bn * 256 + wn * 64 + ccol;
#pragma unroll
    for (int i = 0; i < 8; ++i)
#pragma unroll
        for (int j = 0; j < 4; ++j)
#pragma unroll
            for (int r = 0; r < 4; ++r)
                C[(size_t)(row0 + i * 16 + r) * E + (col0 + j * 16)] = acc[i][j][r];
}

// ------- prep: weight-convert blocks [0,256) + prefilter blocks [256,1284) ----
// prefilter: VG[b, r, e] = sum_j filt[j] * values[b, r-1+j-2, e], 8 rows/thread
// sliding window (1.5x re-read).  cvt: both 512x512 fp32 -> bf16.
__global__ __launch_bounds__(256)
void prep(const float* __restrict__ vals, const float* __restrict__ w_in,
          const float* __restrict__ w_out, bf16* __restrict__ vg,
          bf16* __restrict__ win_b, bf16* __restrict__ wout_b)
{
    const int tid = threadIdx.x;
    const int blk = blockIdx.x;

    if (blk < 256) {                                   // weight convert
        const int i = blk * 256 + tid;                 // [0, 65536)
        const int half = (E * E) / 8;                  // 32768
        const float* src = (i < half) ? w_in : w_out;
        bf16* dst        = (i < half) ? win_b : wout_b;
        const int k = (i < half) ? i : i - half;
        const f32x4* p = (const f32x4*)src + 2 * (size_t)k;
        f32x4 a = p[0], bq = p[1];
        bf16x8 o;
        o[0] = (bf16)a[0];  o[1] = (bf16)a[1];  o[2] = (bf16)a[2];  o[3] = (bf16)a[3];
        o[4] = (bf16)bq[0]; o[5] = (bf16)bq[1]; o[6] = (bf16)bq[2]; o[7] = (bf16)bq[3];
        *((bf16x8*)dst + k) = o;
        return;
    }

    const int e8   = tid & 63;                         // channel chunk (8 floats)
    const int gidx = (blk - 256) * 4 + (tid >> 6);     // row group [0, M1/8)
    const int m0   = gidx << 3;                        // first extended row
    const int b    = m0 / SB;                          // group never straddles batch
    const int r0   = m0 - b * SB;                      // [0, 4112)

    const float filt[5] = {0.05399096651318806f, 0.24197072451914337f,
                           0.3989422804014327f,
                           0.24197072451914337f, 0.05399096651318806f};

    float acc[8][8];
#pragma unroll
    for (int t = 0; t < 8; ++t)
#pragma unroll
        for (int d = 0; d < 8; ++d) acc[t][d] = 0.f;

    const float* bbase = vals + (size_t)b * 4096 * E + e8 * 8;
#pragma unroll
    for (int u = 0; u < 12; ++u) {                     // inputs sp = r0-3 .. r0+8
        const int sp = r0 - 3 + u;
        if (sp >= 0 && sp < 4096) {
            const f32x4* p = (const f32x4*)(bbase + (size_t)sp * E);
            const f32x4 x0 = p[0], x1 = p[1];
            const float x[8] = {x0[0], x0[1], x0[2], x0[3],
                                x1[0], x1[1], x1[2], x1[3]};
#pragma unroll
            for (int t = 0; t < 8; ++t) {              // out row r0+t needs j = u-t
                const int j = u - t;
                if (j >= 0 && j < 5) {
                    const float w = filt[j];
#pragma unroll
                    for (int d = 0; d < 8; ++d) acc[t][d] += w * x[d];
                }
            }
        }
    }
#pragma unroll
    for (int t = 0; t < 8; ++t) {
        bf16x8 o;
#pragma unroll
        for (int d = 0; d < 8; ++d) o[d] = (bf16)acc[t][d];
        *((bf16x8*)vg + (size_t)(m0 + t) * 64 + e8) = o;
    }
}

extern "C" void kernel_launch(void* const* d_in, const int* in_sizes, int n_in,
                              void* d_out, int out_size, void* d_ws, size_t ws_size,
                              hipStream_t stream)
{
    const float* values = (const float*)d_in[0];
    // d_in[1]=keys, d_in[2]=queries: unused by the reference path (no QK^T)
    const float* w_in   = (const float*)d_in[3];
    const float* w_out  = (const float*)d_in[4];
    float* out = (float*)d_out;

    // workspace: weights 1 MB + VG 33.7 MB + P 33.7 MB ~= 68.4 MB
    bf16* win_b  = (bf16*)d_ws;                 // 512*512
    bf16* wout_b = win_b + E * E;               // 512*512
    bf16* vg     = wout_b + E * E;              // M1*E
    bf16* Pbuf   = vg + (size_t)M1 * E;         // M1*E

    prep<<<256 + M1 / 32, 256, 0, stream>>>(values, w_in, w_out, vg, win_b, wout_b);

    // gemm1: 1D grid, bn fastest (4 column-blocks sharing an A-panel adjacent)
    gemm_bt_bf16<<<(M1 / BM) * 4, 256, 0, stream>>>(vg, win_b, Pbuf, M1, E, E);
    // gemm2: 256^2 tiles, exactly 256 blocks (1/CU)
    gemm2_gather<<<(M2 / 256) * 2, 512, 0, stream>>>(Pbuf, wout_b, out);
}